// Round 8
// baseline (88.525 us; speedup 1.0000x reference)
//
#include <hip/hip_runtime.h>
#include <hip/hip_bf16.h>

typedef unsigned short u16;
typedef unsigned int u32;
typedef __attribute__((ext_vector_type(8))) __bf16 bf16x8;
typedef __attribute__((ext_vector_type(4))) float f32x4;

#define NB 4       // batch
#define SQ 4096    // seq len
#define DM 1024    // d_model
#define RPC 4096   // rows per residue class (NB*SQ/4)
#define S4 (4 * DM)

#define VMCNT(n) asm volatile("s_waitcnt vmcnt(" #n ")" ::: "memory")
#define LGKM0()  asm volatile("s_waitcnt lgkmcnt(0)" ::: "memory")
#define BARRIER() asm volatile("s_barrier" ::: "memory")

__device__ __forceinline__ u16 f2b(float f) {
  u32 u = __builtin_bit_cast(u32, f);
  u32 r = u + 0x7fffu + ((u >> 16) & 1u);
  return (u16)(r >> 16);
}
__device__ __forceinline__ u32 cvt2(float lo, float hi) {
  u16 a = __builtin_bit_cast(u16, __float2bfloat16(lo));
  u16 b = __builtin_bit_cast(u16, __float2bfloat16(hi));
  return (u32)a | ((u32)b << 16);
}
__device__ __forceinline__ float dot2(u32 q, u32 k) {
  float ql = __builtin_bit_cast(float, q << 16);
  float qh = __builtin_bit_cast(float, q & 0xffff0000u);
  float kl = __builtin_bit_cast(float, k << 16);
  float kh = __builtin_bit_cast(float, k & 0xffff0000u);
  return ql * kl + qh * kh;
}
__device__ __forceinline__ u32 mul2(u32 v, float p) {
  float lo = __builtin_bit_cast(float, v << 16) * p;
  float hi = __builtin_bit_cast(float, v & 0xffff0000u) * p;
  return (u32)f2b(lo) | ((u32)f2b(hi) << 16);
}
__device__ __forceinline__ void gll16(const void* g, void* l) {
  __builtin_amdgcn_global_load_lds(
      (const __attribute__((address_space(1))) void*)g,
      (__attribute__((address_space(3))) void*)l, 16, 0, 0);
}

// ---- fused prep: pack_x | trans_qkv | trans_wo | bias_pack ----
__global__ __launch_bounds__(256) void prep(const float* __restrict__ x,
                                            const float* __restrict__ Wq,
                                            const float* __restrict__ Wk,
                                            const float* __restrict__ Wv,
                                            const float* __restrict__ Wo,
                                            const float* __restrict__ bq,
                                            const float* __restrict__ bk,
                                            const float* __restrict__ bv,
                                            u16* __restrict__ xbT,
                                            u16* __restrict__ WTp,
                                            u16* __restrict__ WoTp,
                                            float* __restrict__ biasp) {
  __shared__ float T[64][65];
  const int bid = blockIdx.x;
  const int tid = threadIdx.x;
  if (bid < 1024) {
    // ---- pack_x: x -> per-class swizzled bf16 A-tile images ----
    const int wv = tid >> 6, l = tid & 63;
    const int gr0 = bid * 16 + wv * 4;
#pragma unroll
    for (int it = 0; it < 4; ++it) {
      const int gr = gr0 + it;
      const int c = gr >> 12, pr = gr & 4095;
      const int b = pr >> 10;
      const int srow = ((pr & 1023) << 2) + c;
      const int m0 = pr >> 8, rloc = pr & 255;
      const float* src = x + ((size_t)(b * SQ) + srow) * DM;
      u16* dimg = xbT + (size_t)((c * 16 + m0) * 16) * 16384 + rloc * 64;
      const int swzbase = ((((l & 15) >> 1) ^ (rloc & 7)) << 3) + (l & 1) * 4;
#pragma unroll
      for (int i = 0; i < 4; ++i) {
        float4 v = *reinterpret_cast<const float4*>(src + i * 256 + l * 4);
        uint2 pk;
        pk.x = cvt2(v.x, v.y);
        pk.y = cvt2(v.z, v.w);
        const int k64 = i * 4 + (l >> 4);
        *reinterpret_cast<uint2*>(dimg + (size_t)k64 * 16384 + swzbase) = pk;
      }
    }
  } else if (bid < 1792) {
    // ---- trans_qkv: W{q,k,v} -> swizzled B^T tiles [768 N][1024 K], BN=192 ----
    const int q = bid - 1024;
    const int c = q / 192;
    const int rem = q - c * 192;
    const int j0 = (rem >> 4) * 64;
    const int k0 = (rem & 15) * 64;
    const int msel = j0 >> 8;
    const float* W = (msel == 0) ? Wq : ((msel == 1) ? Wk : Wv);
    const int slot = (j0 & 255) >> 6;
    const int colbase = (c + 4 * slot) * 64;
    const int rr = tid >> 6, cc = tid & 63;
#pragma unroll
    for (int it = 0; it < 16; ++it) {
      const int kk = rr + it * 4;
      T[kk][cc] = W[(size_t)(k0 + kk) * 1024 + colbase + cc];
    }
    __syncthreads();
    const int k64 = k0 >> 6;
    const int u = cc >> 3, e = cc & 7;
#pragma unroll
    for (int it = 0; it < 16; ++it) {
      const int jj = rr + it * 4;
      const int j = j0 + jj;
      const int n0 = j / 192, nrow = j - n0 * 192;
      WTp[((size_t)((c * 4 + n0) * 16 + k64)) * 12288 + nrow * 64 + (((u ^ (nrow & 7))) << 3) + e] =
          f2b(T[cc][jj]);
    }
  } else if (bid < 2048) {
    // ---- trans_wo: Wo -> swizzled B^T tiles [1024 N][256 K], BN=256 ----
    const int q = bid - 1792;
    const int c = q >> 6;
    const int rem = q & 63;
    const int e0 = (rem >> 2) * 64;
    const int j0 = (rem & 3) * 64;
    const int rowbase = c * 64 + (j0 >> 6) * 256;
    const int rr = tid >> 6, cc = tid & 63;
#pragma unroll
    for (int it = 0; it < 16; ++it) {
      const int jj = rr + it * 4;
      T[jj][cc] = Wo[(size_t)(rowbase + jj) * 1024 + e0 + cc];
    }
    __syncthreads();
    const int k64 = j0 >> 6;
    const int u = cc >> 3, e = cc & 7;
#pragma unroll
    for (int it = 0; it < 16; ++it) {
      const int ee = rr + it * 4;
      const int n = e0 + ee;
      const int n0 = n >> 8, nrow = n & 255;
      WoTp[((size_t)((c * 4 + n0) * 4 + k64)) * 16384 + nrow * 64 + (((u ^ (nrow & 7))) << 3) + e] =
          f2b(T[cc][ee]);
    }
  } else {
    // ---- bias_pack ----
    const int idx = (bid - 2048) * 256 + tid;
    if (idx < 3072) {
      const int c = idx / 768, j = idx % 768;
      const int msel = j >> 8, jj = j & 255;
      const int col = (c + 4 * (jj >> 6)) * 64 + (jj & 63);
      const float* bb = (msel == 0) ? bq : ((msel == 1) ? bk : bv);
      biasp[idx] = bb[col];
    }
  }
}

// ---- GEMM1: per class, [4096 x 768] = xb(c)[4096 x 1024] @ WTp^T ----
// BM=128, BN=192, BK=64; 4 waves (2Mx2N); 80KB LDS -> 2 blocks/CU.
__global__ __launch_bounds__(256, 2) void gemm_qkv(const u16* __restrict__ xbT,
                                                   const u16* __restrict__ WTp,
                                                   const float* __restrict__ biasp,
                                                   u16* __restrict__ QKV) {
  __shared__ __align__(16) u16 As2[2 * 8192];   // 2 x (128x64) swizzled
  __shared__ __align__(16) u16 Bs2[2 * 12288];  // 2 x (192x64) swizzled
  const int p = blockIdx.x;
  const int L = (p & 7) * 64 + (p >> 3);
  const int c = L >> 7, r = L & 127;
  const int m0 = r >> 2, n0 = r & 3;
  const int tid = threadIdx.x;
  const int lane = tid & 63, w = tid >> 6;
  const int wm = w >> 1, wn = w & 1;
  const int l15 = lane & 15, l16 = lane >> 4;

  const u16* Asrc = xbT + (size_t)((c * 16 + (m0 >> 1)) * 16) * 16384 + (m0 & 1) * 8192;
  const u16* Bsrc = WTp + (size_t)((c * 4 + n0) * 16) * 12288;

  f32x4 acc[4][6];
#pragma unroll
  for (int i = 0; i < 4; ++i)
#pragma unroll
    for (int j = 0; j < 6; ++j) acc[i][j] = (f32x4){0.f, 0.f, 0.f, 0.f};

  int abase[2], bbase[2];
#pragma unroll
  for (int kk = 0; kk < 2; ++kk) {
    const int unit = kk * 4 + l16;
    abase[kk] = (wm * 64 + l15) * 64 + ((unit ^ (l15 & 7)) << 3);
    bbase[kk] = (wn * 96 + l15) * 64 + ((unit ^ (l15 & 7)) << 3);
  }

#define ISSUE_A(kt, buf)                                                   \
  {                                                                        \
    _Pragma("unroll") for (int i = 0; i < 4; ++i)                          \
        gll16(Asrc + (size_t)(kt) * 16384 + i * 2048 + tid * 8,            \
              (char*)As2 + (buf) * 16384 + i * 4096 + tid * 16);           \
  }
#define ISSUE_B(kt, buf)                                                   \
  {                                                                        \
    _Pragma("unroll") for (int i = 0; i < 6; ++i)                          \
        gll16(Bsrc + (size_t)(kt) * 12288 + i * 2048 + tid * 8,            \
              (char*)Bs2 + (buf) * 24576 + i * 4096 + tid * 16);           \
  }

  ISSUE_A(0, 0);
  ISSUE_B(0, 0);
  ISSUE_A(1, 1);
  ISSUE_B(1, 1);
  VMCNT(10);  // tile 0 complete
  BARRIER();

#pragma unroll 1
  for (int t = 0; t < 16; ++t) {
    const u16* Ab = As2 + (t & 1) * 8192;
    const u16* Bb = Bs2 + (t & 1) * 12288;
#pragma unroll
    for (int kk = 0; kk < 2; ++kk) {
      bf16x8 af[4], bv[6];
#pragma unroll
      for (int mf = 0; mf < 4; ++mf)
        af[mf] = *reinterpret_cast<const bf16x8*>(Ab + abase[kk] + mf * 1024);
#pragma unroll
      for (int nf = 0; nf < 6; ++nf)
        bv[nf] = *reinterpret_cast<const bf16x8*>(Bb + bbase[kk] + nf * 1024);
      __builtin_amdgcn_s_setprio(1);
#pragma unroll
      for (int mf = 0; mf < 4; ++mf)
#pragma unroll
        for (int nf = 0; nf < 6; ++nf)
          acc[mf][nf] = __builtin_amdgcn_mfma_f32_16x16x32_bf16(af[mf], bv[nf], acc[mf][nf], 0, 0, 0);
      __builtin_amdgcn_s_setprio(0);
    }
    if (t == 15) break;
    BARRIER();
    if (t <= 13) {
      ISSUE_A(t + 2, t & 1);
      ISSUE_B(t + 2, t & 1);
      VMCNT(10);
    } else {
      VMCNT(0);
    }
    BARRIER();
  }
#undef ISSUE_A
#undef ISSUE_B

  const int rbase = m0 * 128;
  u16* outc = QKV + (size_t)c * RPC * 768;
#pragma unroll
  for (int mf = 0; mf < 4; ++mf) {
#pragma unroll
    for (int nf = 0; nf < 6; ++nf) {
      const int gcol = n0 * 192 + wn * 96 + nf * 16 + l15;
      const float bias = biasp[c * 768 + gcol];
#pragma unroll
      for (int jj = 0; jj < 4; ++jj) {
        const int rowt = wm * 64 + mf * 16 + l16 * 4 + jj;
        outc[(size_t)(rbase + rowt) * 768 + gcol] = f2b(acc[mf][nf][jj] + bias);
      }
    }
  }
}

// ---- fused attention + GEMM2 ----
// Per block (c, m0, n0): 256 rows (= 2 segments) of class c, 256 out cols.
// Prologue: diagonal QK scores + wave-parallel softmax -> pL[slot][row].
// Main loop t=0..3: A tile = p * V-slice (slot t), reg-staged + swizzled
// ds_write; B via counted-vmcnt gll16 double-buffer.  out = A @ Wo + bo.
__global__ __launch_bounds__(512, 1) void attn_out(const u16* __restrict__ QKV,
                                                   const u16* __restrict__ WoTp,
                                                   const float* __restrict__ bo,
                                                   float* __restrict__ out) {
  __shared__ __align__(16) u16 As2[2 * 16384];  // 2 x (256x64) scaled-V, swizzled
  __shared__ __align__(16) u16 Bs2[2 * 16384];  // 2 x (256x64) Wo, swizzled
  __shared__ float pL[1024];                    // [slot][row] scores -> probs
  const int p = blockIdx.x;
  const int L = (p & 7) * 32 + (p >> 3);
  const int c = L >> 6, rem = L & 63;
  const int m0 = rem >> 2, n0 = rem & 3;
  const int tid = threadIdx.x;
  const int lane = tid & 63, w = tid >> 6;
  const int wm = w >> 1, wn = w & 1;
  const int l15 = lane & 15, l16 = lane >> 4;

  const u16* qkv = QKV + ((size_t)c * RPC + m0 * 256) * 768;
  const u16* Bsrc = WoTp + (size_t)((c * 4 + n0) * 4) * 16384;

  // ---- phase 1: diagonal q.k scores (1024 = 256 rows x 4 slots) ----
#pragma unroll
  for (int it = 0; it < 2; ++it) {
    const int idx = tid + it * 512;
    const int row = idx & 255, slot = idx >> 8;  // slots 0,1 then 2,3
    const u16* qp = qkv + (size_t)row * 768 + slot * 64;
    float s = 0.f;
#pragma unroll
    for (int dd = 0; dd < 8; ++dd) {
      uint4 qa = *reinterpret_cast<const uint4*>(qp + dd * 8);
      uint4 ka = *reinterpret_cast<const uint4*>(qp + 256 + dd * 8);
      s += dot2(qa.x, ka.x) + dot2(qa.y, ka.y) + dot2(qa.z, ka.z) + dot2(qa.w, ka.w);
    }
    pL[slot * 256 + row] = s * 0.125f;
  }
  __syncthreads();

  // ---- prefetch V(0) + B(0),B(1) during softmax ----
  const int vrow = tid >> 1;
  const int vq = (tid & 1) * 32;
  const u16* vsrc = qkv + (size_t)vrow * 768 + 512 + vq;
  uint4 vv0, vv1, vv2, vv3;
#define LOADV(kt)                                                          \
  {                                                                        \
    vv0 = *reinterpret_cast<const uint4*>(vsrc + (kt) * 64);               \
    vv1 = *reinterpret_cast<const uint4*>(vsrc + (kt) * 64 + 8);           \
    vv2 = *reinterpret_cast<const uint4*>(vsrc + (kt) * 64 + 16);          \
    vv3 = *reinterpret_cast<const uint4*>(vsrc + (kt) * 64 + 24);          \
  }
#define ISSUE_BO(kt, buf)                                                  \
  {                                                                        \
    _Pragma("unroll") for (int i = 0; i < 4; ++i)                          \
        gll16(Bsrc + (size_t)(kt) * 16384 + i * 4096 + tid * 8,            \
              (char*)Bs2 + (buf) * 32768 + i * 8192 + tid * 16);           \
  }
  const int aw0 = vrow * 64 + ((((tid & 1) * 4) ^ (vrow & 7)) << 3);
  const int aw1 = vrow * 64 + (((((tid & 1) * 4) + 1) ^ (vrow & 7)) << 3);
  const int aw2 = vrow * 64 + (((((tid & 1) * 4) + 2) ^ (vrow & 7)) << 3);
  const int aw3 = vrow * 64 + (((((tid & 1) * 4) + 3) ^ (vrow & 7)) << 3);
#define WRITEA(kt, buf)                                                    \
  {                                                                        \
    const float pr = pL[(kt) * 256 + vrow];                                \
    u16* ab = As2 + (buf) * 16384;                                         \
    uint4 r0, r1, r2, r3;                                                  \
    r0.x = mul2(vv0.x, pr); r0.y = mul2(vv0.y, pr);                        \
    r0.z = mul2(vv0.z, pr); r0.w = mul2(vv0.w, pr);                        \
    r1.x = mul2(vv1.x, pr); r1.y = mul2(vv1.y, pr);                        \
    r1.z = mul2(vv1.z, pr); r1.w = mul2(vv1.w, pr);                        \
    r2.x = mul2(vv2.x, pr); r2.y = mul2(vv2.y, pr);                        \
    r2.z = mul2(vv2.z, pr); r2.w = mul2(vv2.w, pr);                        \
    r3.x = mul2(vv3.x, pr); r3.y = mul2(vv3.y, pr);                        \
    r3.z = mul2(vv3.z, pr); r3.w = mul2(vv3.w, pr);                        \
    *reinterpret_cast<uint4*>(ab + aw0) = r0;                              \
    *reinterpret_cast<uint4*>(ab + aw1) = r1;                              \
    *reinterpret_cast<uint4*>(ab + aw2) = r2;                              \
    *reinterpret_cast<uint4*>(ab + aw3) = r3;                              \
  }

  LOADV(0);        // 4 vmem
  ISSUE_BO(0, 0);  // 4
  ISSUE_BO(1, 1);  // 4   (outstanding: V0,B0,B1 = 12)

  // ---- phase 2: softmax per (slot, segment): 8 waves ----
  {
    const int slot = w >> 1, seg = w & 1;
    float* sv = &pL[slot * 256 + seg * 128];
    const float v0 = sv[lane], v1 = sv[lane + 64];
    float m = fmaxf(v0, v1);
#pragma unroll
    for (int off = 32; off; off >>= 1) m = fmaxf(m, __shfl_xor(m, off));
    const float e0 = __expf(v0 - m), e1 = __expf(v1 - m);
    float ssum = e0 + e1;
#pragma unroll
    for (int off = 32; off; off >>= 1) ssum += __shfl_xor(ssum, off);
    const float inv = 1.f / ssum;
    sv[lane] = e0 * inv;
    sv[lane + 64] = e1 * inv;
  }
  __syncthreads();

  f32x4 acc[4][8];
#pragma unroll
  for (int i = 0; i < 4; ++i)
#pragma unroll
    for (int j = 0; j < 8; ++j) acc[i][j] = (f32x4){0.f, 0.f, 0.f, 0.f};

  int aoff[2][4], boff[2][8];
#pragma unroll
  for (int kk = 0; kk < 2; ++kk) {
    const int unit = kk * 4 + l16;
#pragma unroll
    for (int mf = 0; mf < 4; ++mf) {
      const int rr = wm * 64 + mf * 16 + l15;
      aoff[kk][mf] = rr * 64 + ((unit ^ (rr & 7)) << 3);
    }
#pragma unroll
    for (int nf = 0; nf < 8; ++nf) {
      const int rr = wn * 128 + nf * 16 + l15;
      boff[kk][nf] = rr * 64 + ((unit ^ (rr & 7)) << 3);
    }
  }

  // ---- prologue staging ----
  VMCNT(8);        // V(0) done (retire oldest 4)
  WRITEA(0, 0);
  LOADV(1);        // outstanding: B0,B1,V1 = 12
  VMCNT(8);        // B(0) done
  LGKM0();
  BARRIER();

  // ---- main loop: 4 K-tiles ----
#pragma unroll 1
  for (int t = 0; t < 4; ++t) {
    const u16* Ab = As2 + (t & 1) * 16384;
    const u16* Bb = Bs2 + (t & 1) * 16384;
#pragma unroll
    for (int kk = 0; kk < 2; ++kk) {
      bf16x8 af[4], bvv[8];
#pragma unroll
      for (int mf = 0; mf < 4; ++mf) af[mf] = *reinterpret_cast<const bf16x8*>(Ab + aoff[kk][mf]);
#pragma unroll
      for (int nf = 0; nf < 8; ++nf) bvv[nf] = *reinterpret_cast<const bf16x8*>(Bb + boff[kk][nf]);
      __builtin_amdgcn_s_setprio(1);
#pragma unroll
      for (int mf = 0; mf < 4; ++mf)
#pragma unroll
        for (int nf = 0; nf < 8; ++nf)
          acc[mf][nf] = __builtin_amdgcn_mfma_f32_16x16x32_bf16(af[mf], bvv[nf], acc[mf][nf], 0, 0, 0);
      __builtin_amdgcn_s_setprio(0);
    }
    if (t == 3) break;
    BARRIER();  // buffers t&1 fully consumed
    if (t <= 1) {
      ISSUE_BO(t + 2, t & 1);  // outstanding: B(t+1),V(t+1),B(t+2) = 12
      VMCNT(4);                // retire B(t+1),V(t+1)
    } else {
      VMCNT(0);                // t=2: retire B(3),V(3)
    }
    WRITEA(t + 1, (t + 1) & 1);
    if (t <= 1) LOADV(t + 2);
    LGKM0();
    BARRIER();
  }
#undef LOADV
#undef ISSUE_BO
#undef WRITEA

  // ---- epilogue: bias + fp32 store ----
  const int rbase = m0 * 256;
  const int b = rbase >> 10;
  const int sbase = ((rbase & 1023) << 2) + c;
  float* outp = out + (size_t)(b * SQ + sbase) * DM;
#pragma unroll
  for (int mf = 0; mf < 4; ++mf) {
#pragma unroll
    for (int nf = 0; nf < 8; ++nf) {
      const int gcol = n0 * 256 + wn * 128 + nf * 16 + l15;
      const float bias = bo[gcol];
#pragma unroll
      for (int jj = 0; jj < 4; ++jj) {
        const int rowt = wm * 64 + mf * 16 + l16 * 4 + jj;
        outp[(size_t)rowt * S4 + gcol] = acc[mf][nf][jj] + bias;
      }
    }
  }
}

extern "C" void kernel_launch(void* const* d_in, const int* in_sizes, int n_in,
                              void* d_out, int out_size, void* d_ws, size_t ws_size,
                              hipStream_t stream) {
  const float* x  = (const float*)d_in[0];
  const float* Wq = (const float*)d_in[1];
  const float* bq = (const float*)d_in[2];
  const float* Wk = (const float*)d_in[3];
  const float* bk = (const float*)d_in[4];
  const float* Wv = (const float*)d_in[5];
  const float* bv = (const float*)d_in[6];
  const float* Wo = (const float*)d_in[7];
  const float* bo = (const float*)d_in[8];
  float* out = (float*)d_out;

  // Workspace: xbT 32MB | WoTp 2MB | QKV 25.2MB  (~59MB of 256MB pool)
  char* ws = (char*)d_ws;
  u16* xbT  = (u16*)(ws);              // 4*16*16*16384*2 = 33,554,432
  u16* WoTp = (u16*)(ws + 33554432);   // 4*4*4*16384*2   =  2,097,152
  u16* QKV  = (u16*)(ws + 35651584);   // 4*4096*768*2    = 25,165,824

  // d_out doubles as scratch until attn_out overwrites all of it:
  // WTp @32MB (6.3MB) | biasp @38MB (12KB) — consumed by gemm_qkv only.
  char* ob = (char*)d_out;
  u16*   WTp   = (u16*)(ob + 33554432);
  float* biasp = (float*)(ob + 39845888);

  prep<<<2060, 256, 0, stream>>>(x, Wq, Wk, Wv, Wo, bq, bk, bv, xbT, WTp, WoTp, biasp);
  gemm_qkv<<<512, 256, 0, stream>>>(xbT, WTp, biasp, QKV);
  attn_out<<<256, 512, 0, stream>>>(QKV, WoTp, bo, out);
}